// Round 1
// baseline (570.501 us; speedup 1.0000x reference)
//
#include <hip/hip_runtime.h>
#include <math.h>

#define NTOK 9216      // 96*96 tokens
#define CIN  32        // inner channels
#define CC   64        // outer channels
#define NCHUNKS 8
#define CHUNK 1152     // NTOK / NCHUNKS
#define SM_SHIFT 12.0f

// ---------------- conv 3x3 stride 2 pad 1 ----------------
__global__ void conv3x3_s2(const float* __restrict__ in, const float* __restrict__ w,
                           const float* __restrict__ b, float* __restrict__ out,
                           int Hin, int Hout, int do_lrelu) {
    int o = blockIdx.y;
    __shared__ float wl[CC * 9];
    for (int i = threadIdx.x; i < CC * 9; i += blockDim.x)
        wl[i] = w[o * CC * 9 + i];
    __syncthreads();
    int p = blockIdx.x * blockDim.x + threadIdx.x;
    if (p >= Hout * Hout) return;
    int oh = p / Hout, ow = p % Hout;
    float acc = b[o];
    for (int ci = 0; ci < CC; ++ci) {
        const float* ip = in + ci * Hin * Hin;
        const float* wp = wl + ci * 9;
        #pragma unroll
        for (int kh = 0; kh < 3; ++kh) {
            int ih = oh * 2 - 1 + kh;
            if (ih < 0 || ih >= Hin) continue;
            #pragma unroll
            for (int kw = 0; kw < 3; ++kw) {
                int iw = ow * 2 - 1 + kw;
                if (iw < 0 || iw >= Hin) continue;
                acc = fmaf(ip[ih * Hin + iw], wp[kh * 3 + kw], acc);
            }
        }
    }
    if (do_lrelu) acc = acc >= 0.f ? acc : 0.2f * acc;
    out[o * Hout * Hout + p] = acc;
}

// ---------------- bilinear 12->96 upsample + sigmoid gate ----------------
__global__ void gate_kernel(const float* __restrict__ x, const float* __restrict__ y3,
                            float* __restrict__ xg) {
    int idx = blockIdx.x * 256 + threadIdx.x;   // 64*96*96
    int c = idx / (96 * 96);
    int p = idx % (96 * 96);
    int h = p / 96, w = p % 96;
    float fh = (h + 0.5f) * 0.125f - 0.5f;
    float fw = (w + 0.5f) * 0.125f - 0.5f;
    int h0 = (int)floorf(fh); float ah = fh - (float)h0;
    int w0 = (int)floorf(fw); float aw = fw - (float)w0;
    int h0c = min(max(h0, 0), 11), h1c = min(max(h0 + 1, 0), 11);
    int w0c = min(max(w0, 0), 11), w1c = min(max(w0 + 1, 0), 11);
    const float* yp = y3 + c * 144;
    float v = (1.f - ah) * ((1.f - aw) * yp[h0c * 12 + w0c] + aw * yp[h0c * 12 + w1c])
            +         ah * ((1.f - aw) * yp[h1c * 12 + w0c] + aw * yp[h1c * 12 + w1c]);
    float sg = 1.f / (1.f + __expf(-v));
    xg[idx] = sg * x[idx];
}

// ---------------- three 1x1 convs (g, theta, phi) ----------------
__global__ void conv1x1_3(const float* __restrict__ xg,
                          const float* __restrict__ gw, const float* __restrict__ gb,
                          const float* __restrict__ thw, const float* __restrict__ thb,
                          const float* __restrict__ phw, const float* __restrict__ phb,
                          float* __restrict__ gx, float* __restrict__ tx, float* __restrict__ px) {
    int which = blockIdx.z;
    const float* w  = which == 0 ? gw : (which == 1 ? thw : phw);
    const float* bb = which == 0 ? gb : (which == 1 ? thb : phb);
    float* outp     = which == 0 ? gx : (which == 1 ? tx : px);
    int ci = blockIdx.y;
    int n = blockIdx.x * 256 + threadIdx.x;
    float acc = bb[ci];
    #pragma unroll 8
    for (int c = 0; c < CC; ++c)
        acc = fmaf(w[ci * CC + c], xg[c * NTOK + n], acc);
    outp[ci * NTOK + n] = acc;
}

// ---------------- phase 1: D[m] = sum_n exp(s[n,m]-SHIFT), partial over n-chunks ----------------
__global__ __launch_bounds__(256) void phase1(const float* __restrict__ tx,
                                              const float* __restrict__ px,
                                              float* __restrict__ Dp) {
    __shared__ float pxT[CIN][64];
    __shared__ float txT[CIN][64];
    __shared__ float red[16][64];
    const int m0 = blockIdx.x * 64;
    const int n0 = blockIdx.y * CHUNK;
    const int t = threadIdx.x;
    for (int idx = t; idx < CIN * 64; idx += 256)
        pxT[idx >> 6][idx & 63] = px[(idx >> 6) * NTOK + m0 + (idx & 63)];
    const int mg = t & 15, ng = t >> 4;
    float dsum[4] = {0.f, 0.f, 0.f, 0.f};
    for (int nt = 0; nt < CHUNK; nt += 64) {
        __syncthreads();
        for (int idx = t; idx < CIN * 64; idx += 256)
            txT[idx >> 6][idx & 63] = tx[(idx >> 6) * NTOK + n0 + nt + (idx & 63)];
        __syncthreads();
        float sv[4][4] = {};
        #pragma unroll
        for (int c = 0; c < CIN; ++c) {
            float4 pv = *(const float4*)&pxT[c][4 * mg];
            float4 tv = *(const float4*)&txT[c][4 * ng];
            float pa[4] = {pv.x, pv.y, pv.z, pv.w};
            float ta[4] = {tv.x, tv.y, tv.z, tv.w};
            #pragma unroll
            for (int i = 0; i < 4; ++i)
                #pragma unroll
                for (int j = 0; j < 4; ++j)
                    sv[i][j] = fmaf(ta[i], pa[j], sv[i][j]);
        }
        #pragma unroll
        for (int j = 0; j < 4; ++j) {
            float e = 0.f;
            #pragma unroll
            for (int i = 0; i < 4; ++i) e += __expf(sv[i][j] - SM_SHIFT);
            dsum[j] += e;
        }
    }
    *(float4*)&red[ng][4 * mg] = make_float4(dsum[0], dsum[1], dsum[2], dsum[3]);
    __syncthreads();
    if (t < 64) {
        float s = 0.f;
        #pragma unroll
        for (int g = 0; g < 16; ++g) s += red[g][t];
        Dp[blockIdx.y * NTOK + m0 + t] = s;
    }
}

// ---------------- gd = gx / D (D merged from partials) ----------------
__global__ void gdscale(const float* __restrict__ Dp, float* __restrict__ gx) {
    int idx = blockIdx.x * 256 + threadIdx.x;   // 32*9216
    int m = idx % NTOK;
    float D = 0.f;
    #pragma unroll
    for (int ch = 0; ch < NCHUNKS; ++ch) D += Dp[ch * NTOK + m];
    gx[idx] = gx[idx] / D;
}

// ---------------- phase 2: y2[c,n] = sum_m exp(s[n,m]-SHIFT) * gd[c,m], partial over m-chunks ----------------
__global__ __launch_bounds__(256) void phase2(const float* __restrict__ tx,
                                              const float* __restrict__ px,
                                              const float* __restrict__ gd,
                                              float* __restrict__ y2p) {
    __shared__ float txT[CIN][64];
    __shared__ float pxT[CIN][64];
    __shared__ float gdT[64][36];
    __shared__ float wT[64][68];
    const int n0 = blockIdx.x * 64;
    const int mc0 = blockIdx.y * CHUNK;
    const int t = threadIdx.x;
    for (int idx = t; idx < CIN * 64; idx += 256)
        txT[idx >> 6][idx & 63] = tx[(idx >> 6) * NTOK + n0 + (idx & 63)];
    const int mg = t & 15, ng = t >> 4;
    const int c0 = (t & 7) * 4;
    const int np = t >> 3;          // 0..31, owns n-pair (2*np, 2*np+1)
    const int n_r = 2 * np;
    float acc[2][4] = {{0,0,0,0},{0,0,0,0}};
    for (int mt = 0; mt < CHUNK; mt += 64) {
        const int m0 = mc0 + mt;
        __syncthreads();
        for (int idx = t; idx < CIN * 64; idx += 256) {
            int c = idx >> 6, j = idx & 63;
            pxT[c][j] = px[c * NTOK + m0 + j];
            gdT[j][c] = gd[c * NTOK + m0 + j];
        }
        __syncthreads();
        // stage A: s tile + w = exp(s - SHIFT) into LDS
        float sv[4][4] = {};
        #pragma unroll
        for (int c = 0; c < CIN; ++c) {
            float4 pv = *(const float4*)&pxT[c][4 * mg];
            float4 tv = *(const float4*)&txT[c][4 * ng];
            float pa[4] = {pv.x, pv.y, pv.z, pv.w};
            float ta[4] = {tv.x, tv.y, tv.z, tv.w};
            #pragma unroll
            for (int i = 0; i < 4; ++i)
                #pragma unroll
                for (int j = 0; j < 4; ++j)
                    sv[i][j] = fmaf(ta[i], pa[j], sv[i][j]);
        }
        #pragma unroll
        for (int i = 0; i < 4; ++i) {
            float4 wv;
            wv.x = __expf(sv[i][0] - SM_SHIFT);
            wv.y = __expf(sv[i][1] - SM_SHIFT);
            wv.z = __expf(sv[i][2] - SM_SHIFT);
            wv.w = __expf(sv[i][3] - SM_SHIFT);
            *(float4*)&wT[4 * ng + i][4 * mg] = wv;
        }
        __syncthreads();
        // stage B: acc[c,n] += w[n,m] * gd[c,m]
        #pragma unroll 4
        for (int mi = 0; mi < 64; mi += 4) {
            float4 w0 = *(const float4*)&wT[n_r][mi];
            float4 w1 = *(const float4*)&wT[n_r + 1][mi];
            float w0a[4] = {w0.x, w0.y, w0.z, w0.w};
            float w1a[4] = {w1.x, w1.y, w1.z, w1.w};
            #pragma unroll
            for (int k = 0; k < 4; ++k) {
                float4 g4 = *(const float4*)&gdT[mi + k][c0];
                acc[0][0] = fmaf(w0a[k], g4.x, acc[0][0]);
                acc[0][1] = fmaf(w0a[k], g4.y, acc[0][1]);
                acc[0][2] = fmaf(w0a[k], g4.z, acc[0][2]);
                acc[0][3] = fmaf(w0a[k], g4.w, acc[0][3]);
                acc[1][0] = fmaf(w1a[k], g4.x, acc[1][0]);
                acc[1][1] = fmaf(w1a[k], g4.y, acc[1][1]);
                acc[1][2] = fmaf(w1a[k], g4.z, acc[1][2]);
                acc[1][3] = fmaf(w1a[k], g4.w, acc[1][3]);
            }
        }
    }
    float* yp = y2p + blockIdx.y * (CIN * NTOK);
    #pragma unroll
    for (int j = 0; j < 4; ++j) {
        yp[(c0 + j) * NTOK + n0 + n_r]     = acc[0][j];
        yp[(c0 + j) * NTOK + n0 + n_r + 1] = acc[1][j];
    }
}

// ---------------- merge y2 partials ----------------
__global__ void mergeY2(const float* __restrict__ y2p, float* __restrict__ att) {
    int idx = blockIdx.x * 256 + threadIdx.x;   // 32*9216
    float s = 0.f;
    #pragma unroll
    for (int ch = 0; ch < NCHUNKS; ++ch) s += y2p[ch * (CIN * NTOK) + idx];
    att[idx] = s;
}

// ---------------- final 1x1 conv + residual ----------------
__global__ void final_conv(const float* __restrict__ att, const float* __restrict__ Ww,
                           const float* __restrict__ Wb, const float* __restrict__ xg,
                           float* __restrict__ out) {
    int co = blockIdx.y;
    int n = blockIdx.x * 256 + threadIdx.x;
    float acc = Wb[co];
    #pragma unroll
    for (int ci = 0; ci < CIN; ++ci)
        acc = fmaf(Ww[co * CIN + ci], att[ci * NTOK + n], acc);
    out[co * NTOK + n] = acc + xg[co * NTOK + n];
}

extern "C" void kernel_launch(void* const* d_in, const int* in_sizes, int n_in,
                              void* d_out, int out_size, void* d_ws, size_t ws_size,
                              hipStream_t stream) {
    const float* x   = (const float*)d_in[0];
    const float* d1w = (const float*)d_in[1];  const float* d1b = (const float*)d_in[2];
    const float* d2w = (const float*)d_in[3];  const float* d2b = (const float*)d_in[4];
    const float* d3w = (const float*)d_in[5];  const float* d3b = (const float*)d_in[6];
    const float* gw  = (const float*)d_in[7];  const float* gb  = (const float*)d_in[8];
    const float* thw = (const float*)d_in[9];  const float* thb = (const float*)d_in[10];
    const float* phw = (const float*)d_in[11]; const float* phb = (const float*)d_in[12];
    const float* Ww  = (const float*)d_in[13]; const float* Wb  = (const float*)d_in[14];
    float* out = (float*)d_out;

    float* W    = (float*)d_ws;
    float* xg   = W;                 // 589824
    float* y1   = W + 589824;        // 147456
    float* y2c  = W + 737280;        // 36864
    float* y3   = W + 774144;        // 9216
    float* txb  = W + 783360;        // 294912
    float* pxb  = W + 1078272;       // 294912
    float* gxb  = W + 1373184;       // 294912 (becomes gd in-place)
    float* y2p  = W + 1668096;       // 8*294912
    float* Dp   = W + 4027392;       // 8*9216
    float* att  = W + 4101120;       // 294912

    // gating branch (reads ORIGINAL x)
    conv3x3_s2<<<dim3(9, CC), 256, 0, stream>>>(x,   d1w, d1b, y1,  96, 48, 1);
    conv3x3_s2<<<dim3(3, CC), 256, 0, stream>>>(y1,  d2w, d2b, y2c, 48, 24, 1);
    conv3x3_s2<<<dim3(1, CC), 256, 0, stream>>>(y2c, d3w, d3b, y3,  24, 12, 0);
    gate_kernel<<<2304, 256, 0, stream>>>(x, y3, xg);

    // 1x1 projections
    conv1x1_3<<<dim3(36, CIN, 3), 256, 0, stream>>>(xg, gw, gb, thw, thb, phw, phb,
                                                    gxb, txb, pxb);
    // attention
    phase1<<<dim3(144, NCHUNKS), 256, 0, stream>>>(txb, pxb, Dp);
    gdscale<<<1152, 256, 0, stream>>>(Dp, gxb);
    phase2<<<dim3(144, NCHUNKS), 256, 0, stream>>>(txb, pxb, gxb, y2p);
    mergeY2<<<1152, 256, 0, stream>>>(y2p, att);

    // output
    final_conv<<<dim3(36, CC), 256, 0, stream>>>(att, Ww, Wb, xg, out);
}

// Round 2
// 313.675 us; speedup vs baseline: 1.8188x; 1.8188x over previous
//
#include <hip/hip_runtime.h>
#include <math.h>

#define NTOK 9216      // 96*96 tokens
#define CIN  32        // inner channels
#define CC   64        // outer channels
#define NCH1 8         // phase1 n-chunks
#define NCH2 6         // phase2 m-chunks
#define NT1  72        // n-tiles (16-wide) per phase1 chunk: 576/8
#define MS2  48        // m-steps (32-wide) per phase2 chunk: 9216/6/32
#define SHIFT2 6.4548225555f   // 12 - ln(256)

typedef _Float16 half8 __attribute__((ext_vector_type(8)));
typedef float    f32x4 __attribute__((ext_vector_type(4)));

// ---------------- conv 3x3 stride 2 pad 1 ----------------
__global__ void conv3x3_s2(const float* __restrict__ in, const float* __restrict__ w,
                           const float* __restrict__ b, float* __restrict__ out,
                           int Hin, int Hout, int do_lrelu) {
    int o = blockIdx.y;
    __shared__ float wl[CC * 9];
    for (int i = threadIdx.x; i < CC * 9; i += blockDim.x)
        wl[i] = w[o * CC * 9 + i];
    __syncthreads();
    int p = blockIdx.x * blockDim.x + threadIdx.x;
    if (p >= Hout * Hout) return;
    int oh = p / Hout, ow = p % Hout;
    float acc = b[o];
    for (int ci = 0; ci < CC; ++ci) {
        const float* ip = in + ci * Hin * Hin;
        const float* wp = wl + ci * 9;
        #pragma unroll
        for (int kh = 0; kh < 3; ++kh) {
            int ih = oh * 2 - 1 + kh;
            if (ih < 0 || ih >= Hin) continue;
            #pragma unroll
            for (int kw = 0; kw < 3; ++kw) {
                int iw = ow * 2 - 1 + kw;
                if (iw < 0 || iw >= Hin) continue;
                acc = fmaf(ip[ih * Hin + iw], wp[kh * 3 + kw], acc);
            }
        }
    }
    if (do_lrelu) acc = acc >= 0.f ? acc : 0.2f * acc;
    out[o * Hout * Hout + p] = acc;
}

// ---------------- bilinear 12->96 upsample + sigmoid gate ----------------
__global__ void gate_kernel(const float* __restrict__ x, const float* __restrict__ y3,
                            float* __restrict__ xg) {
    int idx = blockIdx.x * 256 + threadIdx.x;   // 64*96*96
    int c = idx / (96 * 96);
    int p = idx % (96 * 96);
    int h = p / 96, w = p % 96;
    float fh = (h + 0.5f) * 0.125f - 0.5f;
    float fw = (w + 0.5f) * 0.125f - 0.5f;
    int h0 = (int)floorf(fh); float ah = fh - (float)h0;
    int w0 = (int)floorf(fw); float aw = fw - (float)w0;
    int h0c = min(max(h0, 0), 11), h1c = min(max(h0 + 1, 0), 11);
    int w0c = min(max(w0, 0), 11), w1c = min(max(w0 + 1, 0), 11);
    const float* yp = y3 + c * 144;
    float v = (1.f - ah) * ((1.f - aw) * yp[h0c * 12 + w0c] + aw * yp[h0c * 12 + w1c])
            +         ah * ((1.f - aw) * yp[h1c * 12 + w0c] + aw * yp[h1c * 12 + w1c]);
    float sg = 1.f / (1.f + __expf(-v));
    xg[idx] = sg * x[idx];
}

// ---------------- three 1x1 convs (g, theta, phi) ----------------
__global__ void conv1x1_3(const float* __restrict__ xg,
                          const float* __restrict__ gw, const float* __restrict__ gb,
                          const float* __restrict__ thw, const float* __restrict__ thb,
                          const float* __restrict__ phw, const float* __restrict__ phb,
                          float* __restrict__ gx, float* __restrict__ tx, float* __restrict__ px) {
    int which = blockIdx.z;
    const float* w  = which == 0 ? gw : (which == 1 ? thw : phw);
    const float* bb = which == 0 ? gb : (which == 1 ? thb : phb);
    float* outp     = which == 0 ? gx : (which == 1 ? tx : px);
    int ci = blockIdx.y;
    int n = blockIdx.x * 256 + threadIdx.x;
    float acc = bb[ci];
    #pragma unroll 8
    for (int c = 0; c < CC; ++c)
        acc = fmaf(w[ci * CC + c], xg[c * NTOK + n], acc);
    outp[ci * NTOK + n] = acc;
}

// ---------------- repack tx/px (f32 [32][NTOK]) -> fragment-packed f16 ----------------
// tile t (16 n-cols), lane l, elem e holds src[c = (e>>2)*16 + (l>>4)*4 + (e&3)][t*16 + (l&15)]
__global__ void repackAB(const float* __restrict__ tx, const float* __restrict__ px,
                         _Float16* __restrict__ txF, _Float16* __restrict__ pxF) {
    const float* src = blockIdx.y ? px : tx;
    _Float16* dst    = blockIdx.y ? pxF : txF;
    int gid = blockIdx.x * 256 + threadIdx.x;   // 576 tiles * 64 lanes = 36864
    int t = gid >> 6, l = gid & 63;
    int n = t * 16 + (l & 15);
    int khi = (l >> 4) * 4;
    half8 v;
    #pragma unroll
    for (int e = 0; e < 8; ++e) {
        int c = (e >> 2) * 16 + khi + (e & 3);
        v[e] = (_Float16)src[c * NTOK + n];
    }
    *(half8*)(dst + gid * 8) = v;
}

// ---------------- repack gx -> B-fragment-packed f16: [mt32][ct2][64][8] ----------------
// elem e holds gx[c = ct*16 + (l&15)][m0 + (e>>2)*16 + (l>>4)*4 + (e&3)]
__global__ void repackG(const float* __restrict__ gx, _Float16* __restrict__ gxF) {
    __shared__ float lds[CIN][65];
    int m0 = blockIdx.x * 64;
    int tid = threadIdx.x;
    for (int idx = tid; idx < CIN * 64; idx += 256)
        lds[idx >> 6][idx & 63] = gx[(idx >> 6) * NTOK + m0 + (idx & 63)];
    __syncthreads();
    int mt = tid >> 7;            // 0..1 (m-32 subtile)
    int slot = tid & 127;
    int ct = slot >> 6;           // c-tile 0..1
    int l  = slot & 63;
    int khi = (l >> 4) * 4;
    int c = ct * 16 + (l & 15);
    half8 v;
    #pragma unroll
    for (int e = 0; e < 8; ++e) {
        int mloc = (e >> 2) * 16 + khi + (e & 3);
        v[e] = (_Float16)lds[c][mt * 32 + mloc];
    }
    int tile = (blockIdx.x * 2 + mt) * 2 + ct;
    *(half8*)(gxF + tile * 512 + l * 8) = v;
}

// ---------------- phase 1: D[m] = sum_n exp(s[n,m]-12), MFMA, partial over n-chunks ----------------
__global__ __launch_bounds__(256) void phase1(const _Float16* __restrict__ txF,
                                              const _Float16* __restrict__ pxF,
                                              float* __restrict__ Dp) {
    int w = threadIdx.x >> 6, l = threadIdx.x & 63;
    int mtile = blockIdx.x * 4 + w;           // 0..575
    half8 pf = *(const half8*)(pxF + mtile * 512 + l * 8);
    f32x4 zero = {0.f, 0.f, 0.f, 0.f};
    float dsum[4] = {0.f, 0.f, 0.f, 0.f};
    int nt0 = blockIdx.y * NT1;
    for (int i = 0; i < NT1; ++i) {
        half8 tf = *(const half8*)(txF + (nt0 + i) * 512 + l * 8);
        f32x4 s = __builtin_amdgcn_mfma_f32_16x16x32_f16(pf, tf, zero, 0, 0, 0);
        #pragma unroll
        for (int r = 0; r < 4; ++r)
            dsum[r] += __expf(s[r] - 12.0f);
    }
    // sum over n (lanes differing in bits 0..3)
    #pragma unroll
    for (int off = 1; off < 16; off <<= 1)
        #pragma unroll
        for (int r = 0; r < 4; ++r)
            dsum[r] += __shfl_xor(dsum[r], off);
    if ((l & 15) == 0) {
        int m = mtile * 16 + (l >> 4) * 4;
        #pragma unroll
        for (int r = 0; r < 4; ++r)
            Dp[blockIdx.y * NTOK + m + r] = dsum[r];
    }
}

// ---------------- merge D partials -> logD ----------------
__global__ void mergeD(const float* __restrict__ Dp, float* __restrict__ logD) {
    int m = blockIdx.x * 256 + threadIdx.x;
    float D = 0.f;
    #pragma unroll
    for (int ch = 0; ch < NCH1; ++ch) D += Dp[ch * NTOK + m];
    logD[m] = __logf(D);
}

// ---------------- phase 2: y2[c,n] = sum_m f[n,m] gx[c,m], MFMA, partial over m-chunks ----------------
__global__ __launch_bounds__(256) void phase2(const _Float16* __restrict__ txF,
                                              const _Float16* __restrict__ pxF,
                                              const _Float16* __restrict__ gxF,
                                              const float* __restrict__ logD,
                                              float* __restrict__ y2p) {
    int w = threadIdx.x >> 6, l = threadIdx.x & 63;
    int ntile = blockIdx.x * 4 + w;           // 0..575
    half8 tf = *(const half8*)(txF + ntile * 512 + l * 8);
    int khi = (l >> 4) * 4;
    f32x4 zero = {0.f, 0.f, 0.f, 0.f};
    f32x4 acc0 = zero, acc1 = zero;
    int mbase = blockIdx.y * (NTOK / NCH2);
    for (int ms = 0; ms < MS2; ++ms) {
        int m0 = mbase + ms * 32;
        int mt16 = m0 >> 4;
        half8 pf0 = *(const half8*)(pxF + mt16 * 512 + l * 8);
        half8 pf1 = *(const half8*)(pxF + (mt16 + 1) * 512 + l * 8);
        f32x4 s0 = __builtin_amdgcn_mfma_f32_16x16x32_f16(pf0, tf, zero, 0, 0, 0);
        f32x4 s1 = __builtin_amdgcn_mfma_f32_16x16x32_f16(pf1, tf, zero, 0, 0, 0);
        f32x4 ld0 = *(const f32x4*)(logD + m0 + khi);
        f32x4 ld1 = *(const f32x4*)(logD + m0 + 16 + khi);
        half8 ff;
        #pragma unroll
        for (int r = 0; r < 4; ++r) {
            ff[r]     = (_Float16)__expf(s0[r] - SHIFT2 - ld0[r]);
            ff[4 + r] = (_Float16)__expf(s1[r] - SHIFT2 - ld1[r]);
        }
        int gt = (m0 >> 5) * 2;
        half8 gf0 = *(const half8*)(gxF + gt * 512 + l * 8);
        half8 gf1 = *(const half8*)(gxF + (gt + 1) * 512 + l * 8);
        acc0 = __builtin_amdgcn_mfma_f32_16x16x32_f16(ff, gf0, acc0, 0, 0, 0);
        acc1 = __builtin_amdgcn_mfma_f32_16x16x32_f16(ff, gf1, acc1, 0, 0, 0);
    }
    float* base = y2p + blockIdx.y * (CIN * NTOK);
    int n = ntile * 16 + khi;
    #pragma unroll
    for (int r = 0; r < 4; ++r) {
        base[(l & 15) * NTOK + n + r]        = acc0[r] * 0.00390625f;
        base[(16 + (l & 15)) * NTOK + n + r] = acc1[r] * 0.00390625f;
    }
}

// ---------------- merge y2 partials ----------------
__global__ void mergeY2(const float* __restrict__ y2p, float* __restrict__ att) {
    int idx = blockIdx.x * 256 + threadIdx.x;   // 32*9216
    float s = 0.f;
    #pragma unroll
    for (int ch = 0; ch < NCH2; ++ch) s += y2p[ch * (CIN * NTOK) + idx];
    att[idx] = s;
}

// ---------------- final 1x1 conv + residual ----------------
__global__ void final_conv(const float* __restrict__ att, const float* __restrict__ Ww,
                           const float* __restrict__ Wb, const float* __restrict__ xg,
                           float* __restrict__ out) {
    int co = blockIdx.y;
    int n = blockIdx.x * 256 + threadIdx.x;
    float acc = Wb[co];
    #pragma unroll
    for (int ci = 0; ci < CIN; ++ci)
        acc = fmaf(Ww[co * CIN + ci], att[ci * NTOK + n], acc);
    out[co * NTOK + n] = acc + xg[co * NTOK + n];
}

extern "C" void kernel_launch(void* const* d_in, const int* in_sizes, int n_in,
                              void* d_out, int out_size, void* d_ws, size_t ws_size,
                              hipStream_t stream) {
    const float* x   = (const float*)d_in[0];
    const float* d1w = (const float*)d_in[1];  const float* d1b = (const float*)d_in[2];
    const float* d2w = (const float*)d_in[3];  const float* d2b = (const float*)d_in[4];
    const float* d3w = (const float*)d_in[5];  const float* d3b = (const float*)d_in[6];
    const float* gw  = (const float*)d_in[7];  const float* gb  = (const float*)d_in[8];
    const float* thw = (const float*)d_in[9];  const float* thb = (const float*)d_in[10];
    const float* phw = (const float*)d_in[11]; const float* phb = (const float*)d_in[12];
    const float* Ww  = (const float*)d_in[13]; const float* Wb  = (const float*)d_in[14];
    float* out = (float*)d_out;

    float* W    = (float*)d_ws;
    float* xg   = W;                 // 589824
    float* y1   = W + 589824;        // 147456
    float* y2c  = W + 737280;        // 36864
    float* y3   = W + 774144;        // 9216
    float* txb  = W + 783360;        // 294912
    float* pxb  = W + 1078272;       // 294912
    float* gxb  = W + 1373184;       // 294912
    float* Dp   = W + 1668096;       // 8*9216 = 73728
    float* logD = W + 1741824;       // 9216
    float* att  = W + 1751040;       // 294912
    float* y2p  = W + 2045952;       // 6*294912 = 1769472
    _Float16* txF = (_Float16*)(W + 3815424);   // 294912 f16
    _Float16* pxF = (_Float16*)(W + 3962880);   // 294912 f16
    _Float16* gxF = (_Float16*)(W + 4110336);   // 294912 f16  (end: 4257792 floats = 17.0 MB)

    // gating branch (reads ORIGINAL x)
    conv3x3_s2<<<dim3(9, CC), 256, 0, stream>>>(x,   d1w, d1b, y1,  96, 48, 1);
    conv3x3_s2<<<dim3(3, CC), 256, 0, stream>>>(y1,  d2w, d2b, y2c, 48, 24, 1);
    conv3x3_s2<<<dim3(1, CC), 256, 0, stream>>>(y2c, d3w, d3b, y3,  24, 12, 0);
    gate_kernel<<<2304, 256, 0, stream>>>(x, y3, xg);

    // 1x1 projections (f32)
    conv1x1_3<<<dim3(36, CIN, 3), 256, 0, stream>>>(xg, gw, gb, thw, thb, phw, phb,
                                                    gxb, txb, pxb);
    // fragment repack to f16
    repackAB<<<dim3(144, 2), 256, 0, stream>>>(txb, pxb, txF, pxF);
    repackG<<<144, 256, 0, stream>>>(gxb, gxF);

    // attention via MFMA
    phase1<<<dim3(144, NCH1), 256, 0, stream>>>(txF, pxF, Dp);
    mergeD<<<36, 256, 0, stream>>>(Dp, logD);
    phase2<<<dim3(144, NCH2), 256, 0, stream>>>(txF, pxF, gxF, logD, y2p);
    mergeY2<<<1152, 256, 0, stream>>>(y2p, att);

    // output
    final_conv<<<dim3(36, CC), 256, 0, stream>>>(att, Ww, Wb, xg, out);
}